// Round 4
// baseline (88.267 us; speedup 1.0000x reference)
//
#include <hip/hip_runtime.h>

typedef _Float16 h2 __attribute__((ext_vector_type(2)));

#define N_EDGES 4000000
#define N_NODES 100000
#define HID 8
#define NPT 4
#define TWO_LOG2E 2.8853900817779268f
#define LN_EPS 1e-5f

// ws float-slot layout
#define O_GC0 0
#define O_BC0 8
#define O_GC1 16
#define O_BC1 24
#define O_GC2 32
#define O_BC2 40
#define O_B1  48
#define O_B2  56
#define O_B3  64    // 1 float
#define O_W1P 72    // 32 uint slots: packed h2 pairs, [j*4+q]
#define O_W2P 104   // 32
#define O_W3P 136   // 4
#define O_W0C 144   // 48 floats: col-centered W0 (fallback path)
#define O_B0C 192   // 8 floats
#define O_ATAB 256                       // N_NODES*8 floats
#define O_CTAB (256 + N_NODES * HID)     // N_NODES*8 floats
#define WS_FLOATS_NEEDED (256 + 2 * N_NODES * HID)

#if __has_builtin(__builtin_amdgcn_fdot2)
#define FDOT2(a, b, c) __builtin_amdgcn_fdot2((a), (b), (c), false)
#else
#define FDOT2(a, b, c) ((float)(a)[0] * (float)(b)[0] + ((float)(a)[1] * (float)(b)[1] + (c)))
#endif

__global__ void prep_kernel(
    const float* __restrict__ x,
    const float* __restrict__ W0, const float* __restrict__ b0,
    const float* __restrict__ g0, const float* __restrict__ be0,
    const float* __restrict__ W1, const float* __restrict__ b1,
    const float* __restrict__ g1, const float* __restrict__ be1,
    const float* __restrict__ W2, const float* __restrict__ b2,
    const float* __restrict__ g2, const float* __restrict__ be2,
    const float* __restrict__ W3, const float* __restrict__ b3,
    float* __restrict__ ws, int use_tables)
{
    const int tid = threadIdx.x;

    // ---------------- weights prep: block 0, thread 0, serial ----------------
    if (blockIdx.x == 0 && tid == 0) {
        uint* wsu = reinterpret_cast<uint*>(ws);
        for (int j = 0; j < 8; ++j) {
            ws[O_GC0 + j] = g0[j] * TWO_LOG2E;  ws[O_BC0 + j] = be0[j] * TWO_LOG2E;
            ws[O_GC1 + j] = g1[j] * TWO_LOG2E;  ws[O_BC1 + j] = be1[j] * TWO_LOG2E;
            ws[O_GC2 + j] = g2[j] * TWO_LOG2E;  ws[O_BC2 + j] = be2[j] * TWO_LOG2E;
        }
        // W0: center columns (over j) per row; center b0
        {
            float bm = 0.f;
            for (int j = 0; j < 8; ++j) bm += b0[j];
            bm *= 0.125f;
            for (int j = 0; j < 8; ++j) ws[O_B0C + j] = b0[j] - bm;
            for (int k = 0; k < 6; ++k) {
                float rm = 0.f;
                for (int j = 0; j < 8; ++j) rm += W0[k * 8 + j];
                rm *= 0.125f;
                for (int j = 0; j < 8; ++j) ws[O_W0C + k * 8 + j] = W0[k * 8 + j] - rm;
            }
        }
        // W1 / W2: fold tanh affine (-2W), center rows over j, refine in f16, pack
        const float* Ws[2] = {W1, W2};
        const float* bs[2] = {b1, b2};
        const int    wo[2] = {O_W1P, O_W2P};
        const int    bo[2] = {O_B1, O_B2};
        for (int L = 0; L < 2; ++L) {
            const float* W = Ws[L];
            float Wc[64];
            for (int k = 0; k < 8; ++k) {
                float rm = 0.f;
                for (int j = 0; j < 8; ++j) rm += W[k * 8 + j];
                rm *= 0.125f;
                for (int j = 0; j < 8; ++j) Wc[k * 8 + j] = -2.f * (W[k * 8 + j] - rm);
            }
            // refine so f16-rounded rows still have ~zero mean
            for (int k = 0; k < 8; ++k) {
                float m = 0.f;
                for (int j = 0; j < 8; ++j) m += (float)(_Float16)Wc[k * 8 + j];
                m *= 0.125f;
                for (int j = 0; j < 8; ++j) Wc[k * 8 + j] -= m;
            }
            for (int j = 0; j < 8; ++j)
                for (int q = 0; q < 4; ++q) {
                    h2 v;
                    v[0] = (_Float16)Wc[(2 * q) * 8 + j];
                    v[1] = (_Float16)Wc[(2 * q + 1) * 8 + j];
                    wsu[wo[L] + j * 4 + q] = __builtin_bit_cast(uint, v);
                }
            // b' = b + colsum(W), centered over j
            float mb = 0.f, tot = 0.f;
            for (int j = 0; j < 8; ++j) mb += bs[L][j];
            for (int i = 0; i < 64; ++i) tot += W[i];
            for (int j = 0; j < 8; ++j) {
                float cs = 0.f;
                for (int k = 0; k < 8; ++k) cs += W[k * 8 + j];
                ws[bo[L] + j] = bs[L][j] + cs - mb * 0.125f - tot * 0.125f;
            }
        }
        // W3: -2*W3 packed; b3' = b3 + sum(W3)
        {
            float s = 0.f;
            for (int k = 0; k < 8; ++k) s += W3[k];
            ws[O_B3] = b3[0] + s;
            for (int q = 0; q < 4; ++q) {
                h2 v;
                v[0] = (_Float16)(-2.f * W3[2 * q]);
                v[1] = (_Float16)(-2.f * W3[2 * q + 1]);
                wsu[O_W3P + q] = __builtin_bit_cast(uint, v);
            }
        }
    }

    // ---------------- per-node layer-0 tables ----------------
    if (use_tables) {
        const int n = blockIdx.x * blockDim.x + tid;
        if (n < N_NODES) {
            const float x0 = x[n * 3 + 0], x1 = x[n * 3 + 1], x2 = x[n * 3 + 2];
            // recompute centered W0 rows locally (uniform, cheap)
            float bm = 0.f;
            for (int j = 0; j < 8; ++j) bm += b0[j];
            bm *= 0.125f;
            float rm[6];
            for (int k = 0; k < 6; ++k) {
                float m = 0.f;
                for (int j = 0; j < 8; ++j) m += W0[k * 8 + j];
                rm[k] = m * 0.125f;
            }
            float a[8], c[8];
#pragma unroll
            for (int j = 0; j < 8; ++j) {
                a[j] = (b0[j] - bm)
                     + x0 * (W0[0 * 8 + j] - rm[0])
                     + x1 * (W0[1 * 8 + j] - rm[1])
                     + x2 * (W0[2 * 8 + j] - rm[2]);
                c[j] = x0 * (W0[3 * 8 + j] - rm[3])
                     + x1 * (W0[4 * 8 + j] - rm[4])
                     + x2 * (W0[5 * 8 + j] - rm[5]);
            }
            float4* A = reinterpret_cast<float4*>(ws + O_ATAB);
            float4* C = reinterpret_cast<float4*>(ws + O_CTAB);
            A[n * 2 + 0] = make_float4(a[0], a[1], a[2], a[3]);
            A[n * 2 + 1] = make_float4(a[4], a[5], a[6], a[7]);
            C[n * 2 + 0] = make_float4(c[0], c[1], c[2], c[3]);
            C[n * 2 + 1] = make_float4(c[4], c[5], c[6], c[7]);
        }
    }
}

// LN (mean-free) + folded-tanh sigmoid, output packed f16 pairs
__device__ __forceinline__ void ln_pack(const float (&z)[HID],
                                        const float* __restrict__ gc,
                                        const float* __restrict__ bc,
                                        h2 (&p)[4]) {
    float va = 0.f;
#pragma unroll
    for (int j = 0; j < HID; ++j) va = __builtin_fmaf(z[j], z[j], va);
    const float r = __builtin_amdgcn_rsqf(__builtin_fmaf(va, 0.125f, LN_EPS));
    float u[HID];
#pragma unroll
    for (int j = 0; j < HID; ++j) {
        const float s = r * gc[j];
        const float y = __builtin_fmaf(z[j], s, bc[j]);
        const float ex = __builtin_amdgcn_exp2f(y);
        u[j] = __builtin_amdgcn_rcpf(ex + 1.0f);
    }
#pragma unroll
    for (int q = 0; q < 4; ++q)
        p[q] = __builtin_bit_cast(h2, __builtin_amdgcn_cvt_pkrtz(u[2 * q], u[2 * q + 1]));
}

__device__ __forceinline__ void lin8_dot(const h2 (&p)[4],
                                         const uint* __restrict__ wp,
                                         const float* __restrict__ b,
                                         float (&zo)[HID]) {
#pragma unroll
    for (int j = 0; j < HID; ++j) {
        float acc = b[j];
#pragma unroll
        for (int q = 0; q < 4; ++q)
            acc = FDOT2(p[q], __builtin_bit_cast(h2, wp[j * 4 + q]), acc);
        zo[j] = acc;
    }
}

template<bool UT>
__global__ __launch_bounds__(256) void edge_mlp_kernel(
    const float* __restrict__ x,
    const int*   __restrict__ ei,
    const float* __restrict__ ws,
    float* __restrict__ out)
{
    const int t = blockIdx.x * blockDim.x + threadIdx.x;
    const int base = t * NPT;
    if (base >= N_EDGES) return;

    const uint* wsu = reinterpret_cast<const uint*>(ws);
    const int4 sv = *reinterpret_cast<const int4*>(ei + base);
    const int4 dv = *reinterpret_cast<const int4*>(ei + N_EDGES + base);
    const int si[NPT] = {sv.x, sv.y, sv.z, sv.w};
    const int di[NPT] = {dv.x, dv.y, dv.z, dv.w};

    float o[NPT];
#pragma unroll
    for (int e = 0; e < NPT; ++e) {
        float z[HID];
        if (UT) {
            const float4* A = reinterpret_cast<const float4*>(ws + O_ATAB);
            const float4* C = reinterpret_cast<const float4*>(ws + O_CTAB);
            const float4 a0 = A[si[e] * 2], a1 = A[si[e] * 2 + 1];
            const float4 c0 = C[di[e] * 2], c1 = C[di[e] * 2 + 1];
            z[0] = a0.x + c0.x; z[1] = a0.y + c0.y; z[2] = a0.z + c0.z; z[3] = a0.w + c0.w;
            z[4] = a1.x + c1.x; z[5] = a1.y + c1.y; z[6] = a1.z + c1.z; z[7] = a1.w + c1.w;
        } else {
            float xs[3], xd[3];
#pragma unroll
            for (int cc = 0; cc < 3; ++cc) {
                xs[cc] = x[si[e] * 3 + cc];
                xd[cc] = x[di[e] * 3 + cc];
            }
#pragma unroll
            for (int j = 0; j < HID; ++j) {
                float a = __builtin_fmaf(xs[0], ws[O_W0C + 0 * 8 + j], ws[O_B0C + j]);
                a = __builtin_fmaf(xs[1], ws[O_W0C + 1 * 8 + j], a);
                a = __builtin_fmaf(xs[2], ws[O_W0C + 2 * 8 + j], a);
                a = __builtin_fmaf(xd[0], ws[O_W0C + 3 * 8 + j], a);
                a = __builtin_fmaf(xd[1], ws[O_W0C + 4 * 8 + j], a);
                z[j] = __builtin_fmaf(xd[2], ws[O_W0C + 5 * 8 + j], a);
            }
        }

        h2 p[4];
        ln_pack(z, ws + O_GC0, ws + O_BC0, p);
        lin8_dot(p, wsu + O_W1P, ws + O_B1, z);
        ln_pack(z, ws + O_GC1, ws + O_BC1, p);
        lin8_dot(p, wsu + O_W2P, ws + O_B2, z);
        ln_pack(z, ws + O_GC2, ws + O_BC2, p);

        float acc = ws[O_B3];
#pragma unroll
        for (int q = 0; q < 4; ++q)
            acc = FDOT2(p[q], __builtin_bit_cast(h2, wsu[O_W3P + q]), acc);
        o[e] = acc;
    }

    *reinterpret_cast<float4*>(out + base) = make_float4(o[0], o[1], o[2], o[3]);
}

extern "C" void kernel_launch(void* const* d_in, const int* in_sizes, int n_in,
                              void* d_out, int out_size, void* d_ws, size_t ws_size,
                              hipStream_t stream) {
    const float* x   = (const float*)d_in[0];
    const int*   ei  = (const int*)d_in[1];
    const float* W0  = (const float*)d_in[2];
    const float* b0  = (const float*)d_in[3];
    const float* g0  = (const float*)d_in[4];
    const float* be0 = (const float*)d_in[5];
    const float* W1  = (const float*)d_in[6];
    const float* b1  = (const float*)d_in[7];
    const float* g1  = (const float*)d_in[8];
    const float* be1 = (const float*)d_in[9];
    const float* W2  = (const float*)d_in[10];
    const float* b2  = (const float*)d_in[11];
    const float* g2  = (const float*)d_in[12];
    const float* be2 = (const float*)d_in[13];
    const float* W3  = (const float*)d_in[14];
    const float* b3  = (const float*)d_in[15];
    float* out = (float*)d_out;
    float* ws  = (float*)d_ws;

    const bool ut = ws_size >= (size_t)WS_FLOATS_NEEDED * sizeof(float);
    const int prep_blocks = ut ? (N_NODES + 255) / 256 : 1;
    prep_kernel<<<prep_blocks, 256, 0, stream>>>(
        x, W0, b0, g0, be0, W1, b1, g1, be1, W2, b2, g2, be2, W3, b3,
        ws, ut ? 1 : 0);

    const int nthreads = N_EDGES / NPT;          // 1,000,000
    const int blocks = (nthreads + 255) / 256;   // 3907
    if (ut)
        edge_mlp_kernel<true><<<blocks, 256, 0, stream>>>(x, ei, ws, out);
    else
        edge_mlp_kernel<false><<<blocks, 256, 0, stream>>>(x, ei, ws, out);
}

// Round 6
// 54.044 us; speedup vs baseline: 1.6332x; 1.6332x over previous
//
#include <hip/hip_runtime.h>

typedef _Float16 h2 __attribute__((ext_vector_type(2)));

#define N_EDGES 4000000
#define HID 8
#define NPT 4
#define TWO_LOG2E 2.8853900817779268f
#define LN_EPS 1e-5f

// ws float-slot layout (weights only, ~200 floats)
#define O_GC0 0
#define O_BC0 8
#define O_GC1 16
#define O_BC1 24
#define O_GC2 32
#define O_BC2 40
#define O_B1  48
#define O_B2  56
#define O_B3  64    // 1 float
#define O_W1P 72    // 32 uint slots: packed h2 pairs, [j*4+q]
#define O_W2P 104   // 32
#define O_W3P 136   // 4
#define O_W0C 144   // 48 floats: col-centered W0
#define O_B0C 192   // 8 floats

#if __has_builtin(__builtin_amdgcn_fdot2)
#define FDOT2(a, b, c) __builtin_amdgcn_fdot2((a), (b), (c), false)
#else
#define FDOT2(a, b, c) ((float)(a)[0] * (float)(b)[0] + ((float)(a)[1] * (float)(b)[1] + (c)))
#endif

__global__ void prep_kernel(
    const float* __restrict__ W0, const float* __restrict__ b0,
    const float* __restrict__ g0, const float* __restrict__ be0,
    const float* __restrict__ W1, const float* __restrict__ b1,
    const float* __restrict__ g1, const float* __restrict__ be1,
    const float* __restrict__ W2, const float* __restrict__ b2,
    const float* __restrict__ g2, const float* __restrict__ be2,
    const float* __restrict__ W3, const float* __restrict__ b3,
    float* __restrict__ ws)
{
    if (threadIdx.x != 0) return;
    uint* wsu = reinterpret_cast<uint*>(ws);
    for (int j = 0; j < 8; ++j) {
        ws[O_GC0 + j] = g0[j] * TWO_LOG2E;  ws[O_BC0 + j] = be0[j] * TWO_LOG2E;
        ws[O_GC1 + j] = g1[j] * TWO_LOG2E;  ws[O_BC1 + j] = be1[j] * TWO_LOG2E;
        ws[O_GC2 + j] = g2[j] * TWO_LOG2E;  ws[O_BC2 + j] = be2[j] * TWO_LOG2E;
    }
    // W0: center each row's 8 outputs (mean over j) so LN mean == 0; center b0
    {
        float bm = 0.f;
        for (int j = 0; j < 8; ++j) bm += b0[j];
        bm *= 0.125f;
        for (int j = 0; j < 8; ++j) ws[O_B0C + j] = b0[j] - bm;
        for (int k = 0; k < 6; ++k) {
            float rm = 0.f;
            for (int j = 0; j < 8; ++j) rm += W0[k * 8 + j];
            rm *= 0.125f;
            for (int j = 0; j < 8; ++j) ws[O_W0C + k * 8 + j] = W0[k * 8 + j] - rm;
        }
    }
    // W1 / W2: fold tanh affine (h = 1-2u -> W' = -2W, b' = b + colsum(W)),
    // center rows over j, refine in f16, pack as h2 pairs
    const float* Ws[2] = {W1, W2};
    const float* bs[2] = {b1, b2};
    const int    wo[2] = {O_W1P, O_W2P};
    const int    bo[2] = {O_B1, O_B2};
    for (int L = 0; L < 2; ++L) {
        const float* W = Ws[L];
        float Wc[64];
        for (int k = 0; k < 8; ++k) {
            float rm = 0.f;
            for (int j = 0; j < 8; ++j) rm += W[k * 8 + j];
            rm *= 0.125f;
            for (int j = 0; j < 8; ++j) Wc[k * 8 + j] = -2.f * (W[k * 8 + j] - rm);
        }
        for (int k = 0; k < 8; ++k) {  // refine: f16-rounded rows keep ~zero mean
            float m = 0.f;
            for (int j = 0; j < 8; ++j) m += (float)(_Float16)Wc[k * 8 + j];
            m *= 0.125f;
            for (int j = 0; j < 8; ++j) Wc[k * 8 + j] -= m;
        }
        for (int j = 0; j < 8; ++j)
            for (int q = 0; q < 4; ++q) {
                h2 v;
                v[0] = (_Float16)Wc[(2 * q) * 8 + j];
                v[1] = (_Float16)Wc[(2 * q + 1) * 8 + j];
                wsu[wo[L] + j * 4 + q] = __builtin_bit_cast(uint, v);
            }
        float mb = 0.f, tot = 0.f;
        for (int j = 0; j < 8; ++j) mb += bs[L][j];
        for (int i = 0; i < 64; ++i) tot += W[i];
        for (int j = 0; j < 8; ++j) {
            float cs = 0.f;
            for (int k = 0; k < 8; ++k) cs += W[k * 8 + j];
            ws[bo[L] + j] = bs[L][j] + cs - mb * 0.125f - tot * 0.125f;
        }
    }
    // W3: -2*W3 packed; b3' = b3 + sum(W3)
    {
        float s = 0.f;
        for (int k = 0; k < 8; ++k) s += W3[k];
        ws[O_B3] = b3[0] + s;
        for (int q = 0; q < 4; ++q) {
            h2 v;
            v[0] = (_Float16)(-2.f * W3[2 * q]);
            v[1] = (_Float16)(-2.f * W3[2 * q + 1]);
            wsu[O_W3P + q] = __builtin_bit_cast(uint, v);
        }
    }
}

// Mean-free LN + folded-tanh sigmoid u = 1/(1+exp2(y)); pair-rcp halves rcp
// count; outputs packed f16 pairs for dot2.
template<int N>
__device__ __forceinline__ void ln_pack(const float (&z)[N][HID],
                                        const float* __restrict__ gc,
                                        const float* __restrict__ bc,
                                        h2 (&p)[N][4]) {
    float r[N];
#pragma unroll
    for (int e = 0; e < N; ++e) {
        float va = 0.f;
#pragma unroll
        for (int j = 0; j < HID; ++j) va = __builtin_fmaf(z[e][j], z[e][j], va);
        r[e] = __builtin_amdgcn_rsqf(__builtin_fmaf(va, 0.125f, LN_EPS));
    }
    float e1[N][HID];
#pragma unroll
    for (int j = 0; j < HID; ++j) {
        const float gcj = gc[j], bcj = bc[j];
#pragma unroll
        for (int e = 0; e < N; ++e) {
            const float y = __builtin_fmaf(z[e][j], r[e] * gcj, bcj);
            e1[e][j] = __builtin_amdgcn_exp2f(y) + 1.0f;
        }
    }
#pragma unroll
    for (int q = 0; q < 4; ++q)
#pragma unroll
        for (int e = 0; e < N; ++e) {
            const float a = e1[e][2 * q], b = e1[e][2 * q + 1];
            const float pr = __builtin_amdgcn_rcpf(a * b);
            p[e][q] = __builtin_bit_cast(h2,
                __builtin_amdgcn_cvt_pkrtz(b * pr, a * pr));
        }
}

template<int N>
__device__ __forceinline__ void lin8_dot(const h2 (&p)[N][4],
                                         const uint* __restrict__ wp,
                                         const float* __restrict__ b,
                                         float (&zo)[N][HID]) {
#pragma unroll
    for (int j = 0; j < HID; ++j) {
        const float bj = b[j];
        const h2 w0 = __builtin_bit_cast(h2, wp[j * 4 + 0]);
        const h2 w1 = __builtin_bit_cast(h2, wp[j * 4 + 1]);
        const h2 w2 = __builtin_bit_cast(h2, wp[j * 4 + 2]);
        const h2 w3 = __builtin_bit_cast(h2, wp[j * 4 + 3]);
#pragma unroll
        for (int e = 0; e < N; ++e) {
            float acc = FDOT2(p[e][0], w0, bj);
            acc = FDOT2(p[e][1], w1, acc);
            acc = FDOT2(p[e][2], w2, acc);
            zo[e][j] = FDOT2(p[e][3], w3, acc);
        }
    }
}

__global__ __launch_bounds__(256) void edge_mlp_kernel(
    const float* __restrict__ x,
    const int*   __restrict__ ei,
    const float* __restrict__ ws,
    float* __restrict__ out)
{
    const int t = blockIdx.x * blockDim.x + threadIdx.x;
    const int base = t * NPT;
    if (base >= N_EDGES) return;

    const uint* wsu = reinterpret_cast<const uint*>(ws);
    const int4 sv = *reinterpret_cast<const int4*>(ei + base);
    const int4 dv = *reinterpret_cast<const int4*>(ei + N_EDGES + base);
    const int si[NPT] = {sv.x, sv.y, sv.z, sv.w};
    const int di[NPT] = {dv.x, dv.y, dv.z, dv.w};

    float xs[NPT][3], xd[NPT][3];
#pragma unroll
    for (int e = 0; e < NPT; ++e) {
#pragma unroll
        for (int c = 0; c < 3; ++c) {
            xs[e][c] = x[si[e] * 3 + c];
            xd[e][c] = x[di[e] * 3 + c];
        }
    }

    // layer 0 (centered f32 weights)
    float z[NPT][HID];
#pragma unroll
    for (int j = 0; j < HID; ++j) {
        const float w0 = ws[O_W0C + 0 * 8 + j], w1 = ws[O_W0C + 1 * 8 + j],
                    w2 = ws[O_W0C + 2 * 8 + j], w3 = ws[O_W0C + 3 * 8 + j],
                    w4 = ws[O_W0C + 4 * 8 + j], w5 = ws[O_W0C + 5 * 8 + j];
        const float bb = ws[O_B0C + j];
#pragma unroll
        for (int e = 0; e < NPT; ++e) {
            float a = __builtin_fmaf(xs[e][0], w0, bb);
            a = __builtin_fmaf(xs[e][1], w1, a);
            a = __builtin_fmaf(xs[e][2], w2, a);
            a = __builtin_fmaf(xd[e][0], w3, a);
            a = __builtin_fmaf(xd[e][1], w4, a);
            z[e][j] = __builtin_fmaf(xd[e][2], w5, a);
        }
    }

    h2 p[NPT][4];
    ln_pack<NPT>(z, ws + O_GC0, ws + O_BC0, p);
    lin8_dot<NPT>(p, wsu + O_W1P, ws + O_B1, z);
    ln_pack<NPT>(z, ws + O_GC1, ws + O_BC1, p);
    lin8_dot<NPT>(p, wsu + O_W2P, ws + O_B2, z);
    ln_pack<NPT>(z, ws + O_GC2, ws + O_BC2, p);

    // final layer: out = b3' + sum u_k * (-2 W3_k)
    const h2 w30 = __builtin_bit_cast(h2, wsu[O_W3P + 0]);
    const h2 w31 = __builtin_bit_cast(h2, wsu[O_W3P + 1]);
    const h2 w32 = __builtin_bit_cast(h2, wsu[O_W3P + 2]);
    const h2 w33 = __builtin_bit_cast(h2, wsu[O_W3P + 3]);
    const float bb3 = ws[O_B3];
    float o[NPT];
#pragma unroll
    for (int e = 0; e < NPT; ++e) {
        float acc = FDOT2(p[e][0], w30, bb3);
        acc = FDOT2(p[e][1], w31, acc);
        acc = FDOT2(p[e][2], w32, acc);
        o[e] = FDOT2(p[e][3], w33, acc);
    }

    *reinterpret_cast<float4*>(out + base) = make_float4(o[0], o[1], o[2], o[3]);
}

extern "C" void kernel_launch(void* const* d_in, const int* in_sizes, int n_in,
                              void* d_out, int out_size, void* d_ws, size_t ws_size,
                              hipStream_t stream) {
    const float* x   = (const float*)d_in[0];
    const int*   ei  = (const int*)d_in[1];
    const float* W0  = (const float*)d_in[2];
    const float* b0  = (const float*)d_in[3];
    const float* g0  = (const float*)d_in[4];
    const float* be0 = (const float*)d_in[5];
    const float* W1  = (const float*)d_in[6];
    const float* b1  = (const float*)d_in[7];
    const float* g1  = (const float*)d_in[8];
    const float* be1 = (const float*)d_in[9];
    const float* W2  = (const float*)d_in[10];
    const float* b2  = (const float*)d_in[11];
    const float* g2  = (const float*)d_in[12];
    const float* be2 = (const float*)d_in[13];
    const float* W3  = (const float*)d_in[14];
    const float* b3  = (const float*)d_in[15];
    float* out = (float*)d_out;
    float* ws  = (float*)d_ws;

    prep_kernel<<<1, 64, 0, stream>>>(W0, b0, g0, be0, W1, b1, g1, be1,
                                      W2, b2, g2, be2, W3, b3, ws);

    const int nthreads = N_EDGES / NPT;          // 1,000,000
    const int blocks = (nthreads + 255) / 256;   // 3907
    edge_mlp_kernel<<<blocks, 256, 0, stream>>>(x, ei, ws, out);
}